// Round 4
// baseline (727.572 us; speedup 1.0000x reference)
//
#include <hip/hip_runtime.h>
#include <cstddef>

#define F 256
#define H 256
#define NSTRUCT 1000
#define NSPEC 4
#define TM 16      // species padding granularity (one wave's atoms)
#define TPAD 264   // scratch row stride in bf16 elems

typedef __attribute__((ext_vector_type(8))) short bf16x8;
typedef __attribute__((ext_vector_type(4))) float f32x4;

__device__ __forceinline__ unsigned short f2bf(float v) {
  unsigned int u = __float_as_uint(v);
  unsigned int r = (u + 0x7FFFu + ((u >> 16) & 1u)) >> 16;  // RNE
  return (unsigned short)r;
}

__device__ __forceinline__ float bf2f(unsigned short v) {
  return __uint_as_float(((unsigned int)v) << 16);
}

__device__ __forceinline__ unsigned int pack2(float a, float b) {
  return (unsigned int)f2bf(a) | ((unsigned int)f2bf(b) << 16);
}

__device__ __forceinline__ float tanh_fast(float x) {
  x = fminf(fmaxf(x, -15.f), 15.f);
  float e = __expf(2.f * x);
  return __fdividef(e - 1.f, e + 1.f);
}

// ---------------- prep kernels ----------------

// Pack W1, W2, W2^T, W1^T into bf16 MFMA-fragment order, kk-major:
// Out[m][s][kk][jt][lane][i] = W[k][j]  (k = kk*32+(lane>>4)*8+i, j = jt*16+(lane&15))
__global__ void prep_w(const float* __restrict__ W1, const float* __restrict__ W2,
                       unsigned short* __restrict__ Out) {
  int t = blockIdx.x * 256 + threadIdx.x;
  if (t >= 4 * NSPEC * 8192) return;
  int m = t >> 15;              // 0:W1 1:W2 2:W2^T 3:W1^T
  int u = t & 32767;
  int lane = u & 63, jt = (u >> 6) & 15, kk = (u >> 10) & 7, s = u >> 13;
  int trans = (m >= 2);
  const float* In = (m == 0 || m == 3) ? W1 : W2;
  int j = jt * 16 + (lane & 15);
  int k0 = kk * 32 + (lane >> 4) * 8;
  const float* base = In + (size_t)s * F * H;
  unsigned short o[8];
  #pragma unroll
  for (int i = 0; i < 8; ++i) {
    int k = k0 + i;
    float v = trans ? base[(size_t)j * 256 + k] : base[(size_t)k * 256 + j];
    o[i] = f2bf(v);
  }
  *(ushort4*)(Out + (size_t)t * 8) = make_ushort4(o[0], o[1], o[2], o[3]);
  *(ushort4*)(Out + (size_t)t * 8 + 4) = make_ushort4(o[4], o[5], o[6], o[7]);
}

__global__ void histogram_kernel(const int* __restrict__ z, int* __restrict__ cnt, int N) {
  int i = blockIdx.x * blockDim.x + threadIdx.x;
  int lane = threadIdx.x & 63;
  int zi = (i < N) ? z[i] : -1;
  #pragma unroll
  for (int s = 0; s < NSPEC; ++s) {
    unsigned long long m = __ballot(zi == s);
    if (m != 0ull && lane == __ffsll((unsigned long long)m) - 1)
      atomicAdd(&cnt[s], __popcll(m));
  }
}

__global__ void scan_kernel(int* __restrict__ cnt, int* __restrict__ poff) {
  int acc = 0;
  for (int s = 0; s < NSPEC; ++s) {
    poff[s] = acc;
    int padded = ((cnt[s] + TM - 1) / TM) * TM;
    acc += padded;
    cnt[s] = 0;
  }
  poff[NSPEC] = acc;
}

__global__ void scatter_kernel(const int* __restrict__ z, const int* __restrict__ poff,
                               int* __restrict__ cnt, int* __restrict__ perm, int N) {
  int i = blockIdx.x * blockDim.x + threadIdx.x;
  int lane = threadIdx.x & 63;
  int zi = (i < N) ? z[i] : -1;
  #pragma unroll
  for (int s = 0; s < NSPEC; ++s) {
    unsigned long long m = __ballot(zi == s);
    if (m == 0ull) continue;
    int leader = __ffsll((unsigned long long)m) - 1;
    int base = 0;
    if (lane == leader) base = atomicAdd(&cnt[s], __popcll(m));
    base = __shfl(base, leader, 64);
    if (zi == s) {
      int rank = __popcll(m & ((1ull << lane) - 1ull));
      perm[poff[s] + base + rank] = i;
    }
  }
}

// ---------------- fused MFMA MLP fwd+bwd (per-wave private) ----------------

// 16 atoms (A rows) x 256 cols, K=256: 8 kk x 16 jt MFMAs, acc in 64 f32 regs.
__device__ __forceinline__ void gemm_rowfrag(const bf16x8 a[8],
                                             const unsigned short* __restrict__ wf,
                                             int lane, f32x4 acc[16]) {
  #pragma unroll
  for (int jt = 0; jt < 16; ++jt) acc[jt] = (f32x4){0.f, 0.f, 0.f, 0.f};
  #pragma unroll
  for (int kk = 0; kk < 8; ++kk) {
    #pragma unroll
    for (int jt = 0; jt < 16; ++jt) {
      bf16x8 b = *(const bf16x8*)(wf + ((size_t)(kk * 16 + jt) * 64 + lane) * 8);
      acc[jt] = __builtin_amdgcn_mfma_f32_16x16x32_bf16(a[kk], b, acc[jt], 0, 0, 0);
    }
  }
}

__global__ __launch_bounds__(256, 3) void mlp_fused(
    const float* __restrict__ X, const int* __restrict__ smap,
    const unsigned short* __restrict__ Wf,
    const float* __restrict__ b1g, const float* __restrict__ b2g,
    const float* __restrict__ W3g, const float* __restrict__ b3g,
    const float* __restrict__ Wskipg, const float* __restrict__ bskipg,
    const int* __restrict__ perm, const int* __restrict__ poff,
    float* __restrict__ energies, unsigned short* __restrict__ nng)
{
  __shared__ __align__(16) unsigned short scratch[4][16][TPAD];

  const int tid = threadIdx.x;
  const int w = tid >> 6, lane = tid & 63;
  const int l15 = lane & 15, lk = lane >> 4;
  unsigned short (*scr)[TPAD] = scratch[w];

  const int row0 = blockIdx.x * 64 + w * 16;

  int s = 0;
  #pragma unroll
  for (int q = 1; q < NSPEC; ++q)
    if (row0 >= poff[q]) s = q;

  const size_t WMAT = (size_t)NSPEC * 65536;
  const unsigned short* w1f  = Wf + (size_t)s * 65536;
  const unsigned short* w2f  = Wf + WMAT + (size_t)s * 65536;
  const unsigned short* w2tf = Wf + 2 * WMAT + (size_t)s * 65536;
  const unsigned short* w1tf = Wf + 3 * WMAT + (size_t)s * 65536;
  const float* wsk = Wskipg + s * F;

  // ---- phase 0: per-lane X A-frags (atom = l15) + skip-dot partial ----
  const int atomid = perm[row0 + l15];        // this lane's A-frag atom
  int a4[4];                                   // atoms of C-rows lk*4+r
  #pragma unroll
  for (int r = 0; r < 4; ++r) a4[r] = perm[row0 + lk * 4 + r];

  bf16x8 xa[8];
  float xsk = 0.f;
  if (atomid >= 0) {
    const float* xrow = X + (size_t)atomid * F;
    #pragma unroll
    for (int kk = 0; kk < 8; ++kk) {
      const int k0 = kk * 32 + lk * 8;
      float4 u = *(const float4*)(xrow + k0);
      float4 v = *(const float4*)(xrow + k0 + 4);
      float4 wu = *(const float4*)(wsk + k0);
      float4 wv = *(const float4*)(wsk + k0 + 4);
      xsk += u.x * wu.x + u.y * wu.y + u.z * wu.z + u.w * wu.w
           + v.x * wv.x + v.y * wv.y + v.z * wv.z + v.w * wv.w;
      bf16x8 t;
      t[0] = (short)f2bf(u.x); t[1] = (short)f2bf(u.y);
      t[2] = (short)f2bf(u.z); t[3] = (short)f2bf(u.w);
      t[4] = (short)f2bf(v.x); t[5] = (short)f2bf(v.y);
      t[6] = (short)f2bf(v.z); t[7] = (short)f2bf(v.w);
      xa[kk] = t;
    }
  } else {
    #pragma unroll
    for (int kk = 0; kk < 8; ++kk) xa[kk] = (bf16x8){0,0,0,0,0,0,0,0};
  }

  f32x4 acc[16];
  unsigned int t1p[32];  // packed (1 - h1^2), pairs along r

  // ---- GEMM1: h1 = tanh(X @ W1 + b1) -> scratch ----
  __syncthreads();
  gemm_rowfrag(xa, w1f, lane, acc);
  #pragma unroll
  for (int jt = 0; jt < 16; ++jt) {
    const int col = jt * 16 + l15;
    const float b1v = b1g[s * H + col];
    float h0 = tanh_fast(acc[jt][0] + b1v);
    float h1 = tanh_fast(acc[jt][1] + b1v);
    float h2 = tanh_fast(acc[jt][2] + b1v);
    float h3 = tanh_fast(acc[jt][3] + b1v);
    t1p[jt * 2]     = pack2(1.f - h0 * h0, 1.f - h1 * h1);
    t1p[jt * 2 + 1] = pack2(1.f - h2 * h2, 1.f - h3 * h3);
    scr[lk * 4 + 0][col] = f2bf(h0);
    scr[lk * 4 + 1][col] = f2bf(h1);
    scr[lk * 4 + 2][col] = f2bf(h2);
    scr[lk * 4 + 3][col] = f2bf(h3);
  }

  // ---- GEMM2: h2 = tanh(h1 @ W2 + b2); energy; d2 = (1-h2^2)*W3 -> scratch ----
  {
    bf16x8 ha[8];
    #pragma unroll
    for (int kk = 0; kk < 8; ++kk)
      ha[kk] = *(const bf16x8*)&scr[l15][kk * 32 + lk * 8];
    __syncthreads();
    gemm_rowfrag(ha, w2f, lane, acc);
  }
  {
    float ep[4] = {0.f, 0.f, 0.f, 0.f};
    #pragma unroll
    for (int jt = 0; jt < 16; ++jt) {
      const int col = jt * 16 + l15;
      const float b2v = b2g[s * H + col];
      const float w3v = W3g[s * H + col];
      #pragma unroll
      for (int r = 0; r < 4; ++r) {
        float h = tanh_fast(acc[jt][r] + b2v);
        ep[r] += h * w3v;
        scr[lk * 4 + r][col] = f2bf((1.f - h * h) * w3v);
      }
    }
    #pragma unroll
    for (int r = 0; r < 4; ++r) {
      #pragma unroll
      for (int m = 1; m <= 8; m <<= 1)
        ep[r] += __shfl_xor(ep[r], m, 64);
    }
    if (l15 == 0) {
      #pragma unroll
      for (int r = 0; r < 4; ++r)
        if (a4[r] >= 0) atomicAdd(&energies[smap[a4[r]]], ep[r]);
    }
    // skip-connection + biases: reduce xsk over lk groups
    xsk += __shfl_xor(xsk, 16, 64);
    xsk += __shfl_xor(xsk, 32, 64);
    if (lane < 16 && atomid >= 0)
      atomicAdd(&energies[smap[atomid]], xsk + b3g[s] + bskipg[s]);
  }

  // ---- GEMM3: g1 = d2 @ W2^T; d1 = (1-h1^2)*g1 -> scratch ----
  {
    bf16x8 ha[8];
    #pragma unroll
    for (int kk = 0; kk < 8; ++kk)
      ha[kk] = *(const bf16x8*)&scr[l15][kk * 32 + lk * 8];
    __syncthreads();
    gemm_rowfrag(ha, w2tf, lane, acc);
  }
  #pragma unroll
  for (int jt = 0; jt < 16; ++jt) {
    const int col = jt * 16 + l15;
    unsigned int pa = t1p[jt * 2], pb = t1p[jt * 2 + 1];
    scr[lk * 4 + 0][col] = f2bf(acc[jt][0] * bf2f((unsigned short)(pa & 0xffff)));
    scr[lk * 4 + 1][col] = f2bf(acc[jt][1] * bf2f((unsigned short)(pa >> 16)));
    scr[lk * 4 + 2][col] = f2bf(acc[jt][2] * bf2f((unsigned short)(pb & 0xffff)));
    scr[lk * 4 + 3][col] = f2bf(acc[jt][3] * bf2f((unsigned short)(pb >> 16)));
  }

  // ---- GEMM4: dE/dx = d1 @ W1^T + Wskip -> nng (bf16) ----
  {
    bf16x8 ha[8];
    #pragma unroll
    for (int kk = 0; kk < 8; ++kk)
      ha[kk] = *(const bf16x8*)&scr[l15][kk * 32 + lk * 8];
    __syncthreads();
    gemm_rowfrag(ha, w1tf, lane, acc);
  }
  #pragma unroll
  for (int jt = 0; jt < 16; ++jt) {
    const int col = jt * 16 + l15;
    const float wv = wsk[col];
    #pragma unroll
    for (int r = 0; r < 4; ++r)
      if (a4[r] >= 0)
        nng[(size_t)a4[r] * F + col] = f2bf(acc[jt][r] + wv);
  }
}

// ---------------- forces: one wave per pair ----------------

__global__ __launch_bounds__(256) void force_kernel(
    const float* __restrict__ ptg, const int* __restrict__ gmap,
    const unsigned short* __restrict__ g, float* __restrict__ forces, int P)
{
  int w = (int)((blockIdx.x * 256 + threadIdx.x) >> 6);
  int lane = threadIdx.x & 63;
  if (w >= P) return;
  int a = gmap[w];
  ushort4 gu = *(const ushort4*)(g + (size_t)a * F + lane * 4);
  float g0 = bf2f(gu.x), g1 = bf2f(gu.y), g2 = bf2f(gu.z), g3 = bf2f(gu.w);
  const float4* gr = (const float4*)(ptg + (size_t)w * 3 * F);
  float s0, s1, s2;
  {
    float4 t = gr[0 * 64 + lane];
    s0 = t.x * g0 + t.y * g1 + t.z * g2 + t.w * g3;
    t = gr[1 * 64 + lane];
    s1 = t.x * g0 + t.y * g1 + t.z * g2 + t.w * g3;
    t = gr[2 * 64 + lane];
    s2 = t.x * g0 + t.y * g1 + t.z * g2 + t.w * g3;
  }
  #pragma unroll
  for (int off = 32; off >= 1; off >>= 1) {
    s0 += __shfl_xor(s0, off, 64);
    s1 += __shfl_xor(s1, off, 64);
    s2 += __shfl_xor(s2, off, 64);
  }
  float r = (lane == 0) ? s0 : ((lane == 1) ? s1 : s2);
  if (lane < 3) atomicAdd(&forces[(size_t)a * 3 + lane], -r);
}

// ---------------- launch ----------------

extern "C" void kernel_launch(void* const* d_in, const int* in_sizes, int n_in,
                              void* d_out, int out_size, void* d_ws, size_t ws_size,
                              hipStream_t stream) {
  const float* X     = (const float*)d_in[0];
  const int*   z     = (const int*)d_in[1];
  const int*   smap  = (const int*)d_in[2];
  const float* ptg   = (const float*)d_in[3];
  const int*   gmap  = (const int*)d_in[4];
  const float* W1    = (const float*)d_in[5];
  const float* b1    = (const float*)d_in[6];
  const float* W2    = (const float*)d_in[7];
  const float* b2    = (const float*)d_in[8];
  const float* W3    = (const float*)d_in[9];
  const float* b3    = (const float*)d_in[10];
  const float* Wskip = (const float*)d_in[11];
  const float* bskip = (const float*)d_in[12];

  const int N = in_sizes[1];
  const int P = in_sizes[4];

  char* ws = (char*)d_ws;
  int* cnt  = (int*)ws;
  int* poff = (int*)(ws + 16);
  int* perm = (int*)(ws + 64);
  size_t perm_bytes = (size_t)(N + 256) * sizeof(int);
  size_t off = 64 + perm_bytes;
  off = (off + 255) & ~(size_t)255;
  unsigned short* Wf = (unsigned short*)(ws + off);
  const size_t WMAT = (size_t)NSPEC * 65536;
  off += 4 * WMAT * sizeof(unsigned short);
  off = (off + 255) & ~(size_t)255;
  unsigned short* nng = (unsigned short*)(ws + off);  // N * F bf16

  float* energies = (float*)d_out;
  float* forces   = energies + NSTRUCT;

  hipMemsetAsync(d_out, 0, (size_t)out_size * sizeof(float), stream);
  hipMemsetAsync(cnt, 0, 16, stream);
  hipMemsetAsync(perm, 0xFF, perm_bytes, stream);

  prep_w<<<(4 * NSPEC * 8192 + 255) / 256, 256, 0, stream>>>(W1, W2, Wf);

  histogram_kernel<<<(N + 255) / 256, 256, 0, stream>>>(z, cnt, N);
  scan_kernel<<<1, 1, 0, stream>>>(cnt, poff);
  scatter_kernel<<<(N + 255) / 256, 256, 0, stream>>>(z, poff, cnt, perm, N);

  int mlpBlocks = (N + 64 + 63) / 64;   // covers padded total (<= N + 64)
  mlp_fused<<<mlpBlocks, 256, 0, stream>>>(X, smap, Wf, b1, b2, W3, b3,
                                           Wskip, bskip, perm, poff,
                                           energies, nng);

  int forceBlocks = (int)(((size_t)P * 64 + 255) / 256);
  force_kernel<<<forceBlocks, 256, 0, stream>>>(ptg, gmap, nng, forces, P);
}

// Round 5
// 449.301 us; speedup vs baseline: 1.6193x; 1.6193x over previous
//
#include <hip/hip_runtime.h>
#include <cstddef>

#define F 256
#define H 256
#define NSTRUCT 1000
#define NSPEC 4
#define TM 64      // tile rows / species padding granularity
#define TPAD 264   // LDS row stride in bf16 elems (2 lanes/bank on b128)

typedef __attribute__((ext_vector_type(8))) short bf16x8;
typedef __attribute__((ext_vector_type(4))) float f32x4;

__device__ __forceinline__ unsigned short f2bf(float v) {
  unsigned int u = __float_as_uint(v);
  unsigned int r = (u + 0x7FFFu + ((u >> 16) & 1u)) >> 16;  // RNE
  return (unsigned short)r;
}

__device__ __forceinline__ float bf2f(unsigned short v) {
  return __uint_as_float(((unsigned int)v) << 16);
}

__device__ __forceinline__ float tanh_fast(float x) {
  x = fminf(fmaxf(x, -15.f), 15.f);
  float e = __expf(2.f * x);
  return __fdividef(e - 1.f, e + 1.f);
}

// ---------------- prep kernels ----------------

// Pack W1, W2, W2^T, W1^T into bf16 MFMA-fragment order, kk-major:
// Out[m][s][kk][jt][lane][i] = W[k][j]  (k = kk*32+(lane>>4)*8+i, j = jt*16+(lane&15))
__global__ void prep_w(const float* __restrict__ W1, const float* __restrict__ W2,
                       unsigned short* __restrict__ Out) {
  int t = blockIdx.x * 256 + threadIdx.x;
  if (t >= 4 * NSPEC * 8192) return;
  int m = t >> 15;              // 0:W1 1:W2 2:W2^T 3:W1^T
  int u = t & 32767;
  int lane = u & 63, jt = (u >> 6) & 15, kk = (u >> 10) & 7, s = u >> 13;
  int trans = (m >= 2);
  const float* In = (m == 0 || m == 3) ? W1 : W2;
  int j = jt * 16 + (lane & 15);
  int k0 = kk * 32 + (lane >> 4) * 8;
  const float* base = In + (size_t)s * F * H;
  unsigned short o[8];
  #pragma unroll
  for (int i = 0; i < 8; ++i) {
    int k = k0 + i;
    float v = trans ? base[(size_t)j * 256 + k] : base[(size_t)k * 256 + j];
    o[i] = f2bf(v);
  }
  *(ushort4*)(Out + (size_t)t * 8) = make_ushort4(o[0], o[1], o[2], o[3]);
  *(ushort4*)(Out + (size_t)t * 8 + 4) = make_ushort4(o[4], o[5], o[6], o[7]);
}

__global__ void histogram_kernel(const int* __restrict__ z, int* __restrict__ cnt, int N) {
  int i = blockIdx.x * blockDim.x + threadIdx.x;
  int lane = threadIdx.x & 63;
  int zi = (i < N) ? z[i] : -1;
  #pragma unroll
  for (int s = 0; s < NSPEC; ++s) {
    unsigned long long m = __ballot(zi == s);
    if (m != 0ull && lane == __ffsll((unsigned long long)m) - 1)
      atomicAdd(&cnt[s], __popcll(m));
  }
}

__global__ void scan_kernel(int* __restrict__ cnt, int* __restrict__ poff) {
  int acc = 0;
  for (int s = 0; s < NSPEC; ++s) {
    poff[s] = acc;
    int padded = ((cnt[s] + TM - 1) / TM) * TM;
    acc += padded;
    cnt[s] = 0;
  }
  poff[NSPEC] = acc;
}

__global__ void scatter_kernel(const int* __restrict__ z, const int* __restrict__ poff,
                               int* __restrict__ cnt, int* __restrict__ perm,
                               int* __restrict__ inv, int N) {
  int i = blockIdx.x * blockDim.x + threadIdx.x;
  int lane = threadIdx.x & 63;
  int zi = (i < N) ? z[i] : -1;
  #pragma unroll
  for (int s = 0; s < NSPEC; ++s) {
    unsigned long long m = __ballot(zi == s);
    if (m == 0ull) continue;
    int leader = __ffsll((unsigned long long)m) - 1;
    int base = 0;
    if (lane == leader) base = atomicAdd(&cnt[s], __popcll(m));
    base = __shfl(base, leader, 64);
    if (zi == s) {
      int rank = __popcll(m & ((1ull << lane) - 1ull));
      int pos = poff[s] + base + rank;
      perm[pos] = i;
      inv[i] = pos;
    }
  }
}

// ---------------- GEMM cores ----------------

// 64x256 @ 256x256: 8 waves; wave w -> col-tiles {2w, 2w+1}; A from LDS [64][TPAD].
__device__ __forceinline__ void gemm64(const unsigned short (*src)[TPAD],
                                       const unsigned short* __restrict__ wf,
                                       int w, int lane, f32x4 acc[4][2]) {
  const int l15 = lane & 15, lk = lane >> 4;
  #pragma unroll
  for (int rt = 0; rt < 4; ++rt)
    #pragma unroll
    for (int q = 0; q < 2; ++q) acc[rt][q] = (f32x4){0.f, 0.f, 0.f, 0.f};
  #pragma unroll
  for (int kk = 0; kk < 8; ++kk) {
    const int kcol = kk * 32 + lk * 8;
    bf16x8 a0 = *(const bf16x8*)&src[l15][kcol];
    bf16x8 a1 = *(const bf16x8*)&src[16 + l15][kcol];
    bf16x8 a2 = *(const bf16x8*)&src[32 + l15][kcol];
    bf16x8 a3 = *(const bf16x8*)&src[48 + l15][kcol];
    #pragma unroll
    for (int q = 0; q < 2; ++q) {
      const int jt = w * 2 + q;
      bf16x8 b = *(const bf16x8*)(wf + ((size_t)(kk * 16 + jt) * 64 + lane) * 8);
      acc[0][q] = __builtin_amdgcn_mfma_f32_16x16x32_bf16(a0, b, acc[0][q], 0, 0, 0);
      acc[1][q] = __builtin_amdgcn_mfma_f32_16x16x32_bf16(a1, b, acc[1][q], 0, 0, 0);
      acc[2][q] = __builtin_amdgcn_mfma_f32_16x16x32_bf16(a2, b, acc[2][q], 0, 0, 0);
      acc[3][q] = __builtin_amdgcn_mfma_f32_16x16x32_bf16(a3, b, acc[3][q], 0, 0, 0);
    }
  }
}

// Same, but A-frags from flat fragment-packed LDS: [rt][kk][lane][8].
__device__ __forceinline__ void gemm64f(const unsigned short* __restrict__ src,
                                        const unsigned short* __restrict__ wf,
                                        int w, int lane, f32x4 acc[4][2]) {
  #pragma unroll
  for (int rt = 0; rt < 4; ++rt)
    #pragma unroll
    for (int q = 0; q < 2; ++q) acc[rt][q] = (f32x4){0.f, 0.f, 0.f, 0.f};
  #pragma unroll
  for (int kk = 0; kk < 8; ++kk) {
    bf16x8 a0 = *(const bf16x8*)(src + ((size_t)(0 * 8 + kk) * 64 + lane) * 8);
    bf16x8 a1 = *(const bf16x8*)(src + ((size_t)(1 * 8 + kk) * 64 + lane) * 8);
    bf16x8 a2 = *(const bf16x8*)(src + ((size_t)(2 * 8 + kk) * 64 + lane) * 8);
    bf16x8 a3 = *(const bf16x8*)(src + ((size_t)(3 * 8 + kk) * 64 + lane) * 8);
    #pragma unroll
    for (int q = 0; q < 2; ++q) {
      const int jt = w * 2 + q;
      bf16x8 b = *(const bf16x8*)(wf + ((size_t)(kk * 16 + jt) * 64 + lane) * 8);
      acc[0][q] = __builtin_amdgcn_mfma_f32_16x16x32_bf16(a0, b, acc[0][q], 0, 0, 0);
      acc[1][q] = __builtin_amdgcn_mfma_f32_16x16x32_bf16(a1, b, acc[1][q], 0, 0, 0);
      acc[2][q] = __builtin_amdgcn_mfma_f32_16x16x32_bf16(a2, b, acc[2][q], 0, 0, 0);
      acc[3][q] = __builtin_amdgcn_mfma_f32_16x16x32_bf16(a3, b, acc[3][q], 0, 0, 0);
    }
  }
}

// ---------------- K12: forward (GEMM1+GEMM2), energies, d2/t1 emission ----------------

__global__ __launch_bounds__(512, 6) void k12(
    const float* __restrict__ X, const int* __restrict__ smap,
    const unsigned short* __restrict__ Wf,
    const float* __restrict__ b1g, const float* __restrict__ b2g,
    const float* __restrict__ W3g, const float* __restrict__ b3g,
    const float* __restrict__ Wskipg, const float* __restrict__ bskipg,
    const int* __restrict__ perm, const int* __restrict__ poff,
    float* __restrict__ energies,
    unsigned short* __restrict__ t1c, unsigned short* __restrict__ d2p)
{
  __shared__ __align__(16) unsigned short buf[TM][TPAD];
  __shared__ float xskp[TM][8];
  __shared__ float e_lds[TM];
  __shared__ int atom_l[TM];

  const int tid = threadIdx.x;
  const int row0 = blockIdx.x * TM;
  if (row0 >= poff[NSPEC]) return;

  int s = 0;
  #pragma unroll
  for (int q = 1; q < NSPEC; ++q)
    if (row0 >= poff[q]) s = q;

  const size_t WMAT = (size_t)NSPEC * 65536;
  const unsigned short* w1f = Wf + (size_t)s * 65536;
  const unsigned short* w2f = Wf + WMAT + (size_t)s * 65536;
  const float* wsk = Wskipg + s * F;

  // ---- phase 0: stage X (fp32->bf16) + skip-dot partials ----
  {
    const int lr = tid >> 3, lc = tid & 7;
    if (tid < TM) { e_lds[tid] = 0.f; atom_l[tid] = perm[row0 + tid]; }
    const int atomR = perm[row0 + lr];
    float xsk = 0.f;
    if (atomR >= 0) {
      const float4* xrow = (const float4*)(X + (size_t)atomR * F);
      #pragma unroll
      for (int jj = 0; jj < 8; ++jj) {
        const int fi = lc + jj * 8;
        float4 v = xrow[fi];
        float4 wv = ((const float4*)wsk)[fi];
        xsk += v.x * wv.x + v.y * wv.y + v.z * wv.z + v.w * wv.w;
        *(ushort4*)&buf[lr][fi * 4] =
            make_ushort4(f2bf(v.x), f2bf(v.y), f2bf(v.z), f2bf(v.w));
      }
    } else {
      #pragma unroll
      for (int jj = 0; jj < 8; ++jj)
        *(ushort4*)&buf[lr][(lc + jj * 8) * 4] = make_ushort4(0, 0, 0, 0);
    }
    xskp[lr][lc] = xsk;
  }
  __syncthreads();

  const int w = tid >> 6, lane = tid & 63;
  const int l15 = lane & 15, lk = lane >> 4;
  f32x4 acc[4][2];

  // ---- GEMM1 ----
  gemm64(buf, w1f, w, lane, acc);
  __syncthreads();  // all X reads complete

  // epilogue: h1 -> buf; t1 = 1-h1^2 -> t1c (per-thread C-order, coalesced)
  {
    unsigned short tv[32];
    #pragma unroll
    for (int q = 0; q < 2; ++q) {
      const int col = (w * 2 + q) * 16 + l15;
      const float b1v = b1g[s * H + col];
      #pragma unroll
      for (int rt = 0; rt < 4; ++rt)
        #pragma unroll
        for (int r = 0; r < 4; ++r) {
          float h = tanh_fast(acc[rt][q][r] + b1v);
          buf[rt * 16 + lk * 4 + r][col] = f2bf(h);
          tv[(q * 4 + rt) * 4 + r] = f2bf(1.f - h * h);
        }
    }
    size_t tbase = (size_t)blockIdx.x * 16384;
    #pragma unroll
    for (int k = 0; k < 4; ++k)
      *(uint4*)(t1c + tbase + (size_t)k * 4096 + tid * 8) = *(uint4*)&tv[k * 8];
  }
  __syncthreads();

  // ---- GEMM2 ----
  gemm64(buf, w2f, w, lane, acc);
  __syncthreads();  // all h1 reads complete

  // epilogue: h2 -> energy partials; d2 = (1-h2^2)*W3 -> buf
  {
    float ep[4][4];
    #pragma unroll
    for (int rt = 0; rt < 4; ++rt)
      #pragma unroll
      for (int r = 0; r < 4; ++r) ep[rt][r] = 0.f;
    #pragma unroll
    for (int q = 0; q < 2; ++q) {
      const int col = (w * 2 + q) * 16 + l15;
      const float b2v = b2g[s * H + col];
      const float w3v = W3g[s * H + col];
      #pragma unroll
      for (int rt = 0; rt < 4; ++rt)
        #pragma unroll
        for (int r = 0; r < 4; ++r) {
          float h = tanh_fast(acc[rt][q][r] + b2v);
          ep[rt][r] += h * w3v;
          buf[rt * 16 + lk * 4 + r][col] = f2bf((1.f - h * h) * w3v);
        }
    }
    #pragma unroll
    for (int rt = 0; rt < 4; ++rt)
      #pragma unroll
      for (int r = 0; r < 4; ++r) {
        #pragma unroll
        for (int m = 1; m <= 8; m <<= 1)
          ep[rt][r] += __shfl_xor(ep[rt][r], m, 64);
      }
    if (l15 == 0) {
      #pragma unroll
      for (int rt = 0; rt < 4; ++rt)
        #pragma unroll
        for (int r = 0; r < 4; ++r)
          atomicAdd(&e_lds[rt * 16 + lk * 4 + r], ep[rt][r]);
    }
  }
  __syncthreads();

  // ---- store d2 fragment-packed (wave w owns rt=w>>1, kk0=(w&1)*4) ----
  {
    const int rt_s = w >> 1, kk0 = (w & 1) * 4;
    size_t dbase = (size_t)blockIdx.x * 16384;
    #pragma unroll
    for (int j = 0; j < 4; ++j) {
      int kk = kk0 + j;
      bf16x8 v = *(const bf16x8*)&buf[rt_s * 16 + l15][kk * 32 + lk * 8];
      *(bf16x8*)(d2p + dbase + ((size_t)(rt_s * 8 + kk) * 64 + lane) * 8) = v;
    }
  }

  // ---- energies finalize ----
  if (tid < TM) {
    int atom = atom_l[tid];
    if (atom >= 0) {
      float xs = 0.f;
      #pragma unroll
      for (int q = 0; q < 8; ++q) xs += xskp[tid][q];
      atomicAdd(&energies[smap[atom]], e_lds[tid] + xs + b3g[s] + bskipg[s]);
    }
  }
}

// ---------------- K34: backward (GEMM3+GEMM4) -> nng (in-place over d2p, slot-indexed) ----------------

__global__ __launch_bounds__(512, 6) void k34(
    const unsigned short* __restrict__ Wf, const float* __restrict__ Wskipg,
    const int* __restrict__ poff,
    const unsigned short* __restrict__ t1c, unsigned short* __restrict__ dng)
{
  __shared__ __align__(16) unsigned short buf[TM][TPAD];

  const int tid = threadIdx.x;
  const int row0 = blockIdx.x * TM;
  if (row0 >= poff[NSPEC]) return;

  int s = 0;
  #pragma unroll
  for (int q = 1; q < NSPEC; ++q)
    if (row0 >= poff[q]) s = q;

  const size_t WMAT = (size_t)NSPEC * 65536;
  const unsigned short* w2tf = Wf + 2 * WMAT + (size_t)s * 65536;
  const unsigned short* w1tf = Wf + 3 * WMAT + (size_t)s * 65536;
  const float* wsk = Wskipg + s * F;

  unsigned short* flat = &buf[0][0];
  const size_t dbase = (size_t)blockIdx.x * 16384;

  // ---- stage packed d2 tile -> LDS (flat copy) ----
  #pragma unroll
  for (int i = 0; i < 4; ++i) {
    int idx = tid + i * 512;
    *(uint4*)(flat + (size_t)idx * 8) = *(const uint4*)(dng + dbase + (size_t)idx * 8);
  }
  __syncthreads();

  const int w = tid >> 6, lane = tid & 63;
  const int l15 = lane & 15, lk = lane >> 4;
  f32x4 acc[4][2];

  // ---- GEMM3: g1 = d2 @ W2^T ----
  gemm64f(flat, w2tf, w, lane, acc);

  // t1 load (independent; overlaps)
  unsigned short tv[32];
  {
    size_t tbase = (size_t)blockIdx.x * 16384;
    #pragma unroll
    for (int k = 0; k < 4; ++k)
      *(uint4*)&tv[k * 8] = *(const uint4*)(t1c + tbase + (size_t)k * 4096 + tid * 8);
  }
  __syncthreads();  // staged d2 reads complete before overwrite

  // d1 = t1 * g1 -> buf
  #pragma unroll
  for (int q = 0; q < 2; ++q) {
    const int col = (w * 2 + q) * 16 + l15;
    #pragma unroll
    for (int rt = 0; rt < 4; ++rt)
      #pragma unroll
      for (int r = 0; r < 4; ++r) {
        float d = bf2f(tv[(q * 4 + rt) * 4 + r]) * acc[rt][q][r];
        buf[rt * 16 + lk * 4 + r][col] = f2bf(d);
      }
  }
  __syncthreads();

  // ---- GEMM4: nng = d1 @ W1^T + Wskip (slot-indexed rows, in-place) ----
  gemm64(buf, w1tf, w, lane, acc);
  #pragma unroll
  for (int q = 0; q < 2; ++q) {
    const int col = (w * 2 + q) * 16 + l15;
    const float wv = wsk[col];
    #pragma unroll
    for (int rt = 0; rt < 4; ++rt)
      #pragma unroll
      for (int r = 0; r < 4; ++r) {
        int slot = row0 + rt * 16 + lk * 4 + r;
        dng[(size_t)slot * 256 + col] = f2bf(acc[rt][q][r] + wv);
      }
  }
}

// ---------------- forces: one wave per pair ----------------

__global__ __launch_bounds__(256) void force_kernel(
    const float* __restrict__ ptg, const int* __restrict__ gmap,
    const int* __restrict__ inv, const unsigned short* __restrict__ g,
    float* __restrict__ forces, int P)
{
  int w = (int)((blockIdx.x * 256 + threadIdx.x) >> 6);
  int lane = threadIdx.x & 63;
  if (w >= P) return;
  int a = gmap[w];
  int slot = inv[a];
  ushort4 gu = *(const ushort4*)(g + (size_t)slot * 256 + lane * 4);
  float g0 = bf2f(gu.x), g1 = bf2f(gu.y), g2 = bf2f(gu.z), g3 = bf2f(gu.w);
  const float4* gr = (const float4*)(ptg + (size_t)w * 3 * F);
  float s0, s1, s2;
  {
    float4 t = gr[0 * 64 + lane];
    s0 = t.x * g0 + t.y * g1 + t.z * g2 + t.w * g3;
    t = gr[1 * 64 + lane];
    s1 = t.x * g0 + t.y * g1 + t.z * g2 + t.w * g3;
    t = gr[2 * 64 + lane];
    s2 = t.x * g0 + t.y * g1 + t.z * g2 + t.w * g3;
  }
  #pragma unroll
  for (int off = 32; off >= 1; off >>= 1) {
    s0 += __shfl_xor(s0, off, 64);
    s1 += __shfl_xor(s1, off, 64);
    s2 += __shfl_xor(s2, off, 64);
  }
  float r = (lane == 0) ? s0 : ((lane == 1) ? s1 : s2);
  if (lane < 3) atomicAdd(&forces[(size_t)a * 3 + lane], -r);
}

// ---------------- launch ----------------

extern "C" void kernel_launch(void* const* d_in, const int* in_sizes, int n_in,
                              void* d_out, int out_size, void* d_ws, size_t ws_size,
                              hipStream_t stream) {
  const float* X     = (const float*)d_in[0];
  const int*   z     = (const int*)d_in[1];
  const int*   smap  = (const int*)d_in[2];
  const float* ptg   = (const float*)d_in[3];
  const int*   gmap  = (const int*)d_in[4];
  const float* W1    = (const float*)d_in[5];
  const float* b1    = (const float*)d_in[6];
  const float* W2    = (const float*)d_in[7];
  const float* b2    = (const float*)d_in[8];
  const float* W3    = (const float*)d_in[9];
  const float* b3    = (const float*)d_in[10];
  const float* Wskip = (const float*)d_in[11];
  const float* bskip = (const float*)d_in[12];

  const int N = in_sizes[1];
  const int P = in_sizes[4];
  const int tiles = (N + NSPEC * TM + TM - 1) / TM;  // upper bound on padded tiles

  char* ws = (char*)d_ws;
  int* cnt  = (int*)ws;
  int* poff = (int*)(ws + 16);
  int* perm = (int*)(ws + 64);
  size_t perm_bytes = (size_t)(N + NSPEC * TM) * sizeof(int);
  size_t off = 64 + perm_bytes;
  off = (off + 255) & ~(size_t)255;
  int* inv = (int*)(ws + off); off += (size_t)N * sizeof(int);
  off = (off + 255) & ~(size_t)255;
  unsigned short* Wf = (unsigned short*)(ws + off);
  const size_t WMAT = (size_t)NSPEC * 65536;
  off += 4 * WMAT * sizeof(unsigned short);
  off = (off + 255) & ~(size_t)255;
  unsigned short* t1c = (unsigned short*)(ws + off);
  off += (size_t)tiles * 16384 * sizeof(unsigned short);
  off = (off + 255) & ~(size_t)255;
  unsigned short* dng = (unsigned short*)(ws + off);  // d2 packed, then nng (slot-major)

  float* energies = (float*)d_out;
  float* forces   = energies + NSTRUCT;

  hipMemsetAsync(d_out, 0, (size_t)out_size * sizeof(float), stream);
  hipMemsetAsync(cnt, 0, 16, stream);
  hipMemsetAsync(perm, 0xFF, perm_bytes, stream);

  prep_w<<<(4 * NSPEC * 8192 + 255) / 256, 256, 0, stream>>>(W1, W2, Wf);

  histogram_kernel<<<(N + 255) / 256, 256, 0, stream>>>(z, cnt, N);
  scan_kernel<<<1, 1, 0, stream>>>(cnt, poff);
  scatter_kernel<<<(N + 255) / 256, 256, 0, stream>>>(z, poff, cnt, perm, inv, N);

  k12<<<tiles, 512, 0, stream>>>(X, smap, Wf, b1, b2, W3, b3, Wskip, bskip,
                                 perm, poff, energies, t1c, dng);
  k34<<<tiles, 512, 0, stream>>>(Wf, Wskip, poff, t1c, dng);

  int forceBlocks = (int)(((size_t)P * 64 + 255) / 256);
  force_kernel<<<forceBlocks, 256, 0, stream>>>(ptg, gmap, inv, dng, forces, P);
}